// Round 5
// baseline (1002.126 us; speedup 1.0000x reference)
//
#include <hip/hip_runtime.h>
#include <cstdint>
#include <cstddef>

typedef __bf16 bf16_t;
typedef __bf16 bf16x8 __attribute__((ext_vector_type(8)));
typedef __bf16 bf16x4 __attribute__((ext_vector_type(4)));
typedef float floatx4 __attribute__((ext_vector_type(4)));

// ---------------------------------------------------------------- helpers
__device__ __forceinline__ void async16(const bf16_t* g, bf16_t* l) {
  __builtin_amdgcn_global_load_lds(
      (const __attribute__((address_space(1))) unsigned int*)g,
      (__attribute__((address_space(3))) unsigned int*)l, 16, 0, 0);
}

// Barrier draining ONLY lgkmcnt — keeps prefetch global loads in flight.
__device__ __forceinline__ void barrier_lds() {
  asm volatile("s_waitcnt lgkmcnt(0)\n\ts_barrier" ::: "memory");
}

__device__ __forceinline__ float siluf(float x) { return x / (1.f + __expf(-x)); }

#define MFMA16(a, b, c) __builtin_amdgcn_mfma_f32_16x16x32_bf16(a, b, c, 0, 0, 0)

// ---------------------------------------------------------------- fp32 -> bf16 (all 4 tensors)
__global__ __launch_bounds__(256) void k_cvt_all(const float* __restrict__ hid,
                                                 const float* __restrict__ wq,
                                                 const float* __restrict__ wzp,
                                                 const float* __restrict__ wo,
                                                 bf16_t* __restrict__ oh,
                                                 bf16_t* __restrict__ oq,
                                                 bf16_t* __restrict__ oz,
                                                 bf16_t* __restrict__ oo) {
  int i = blockIdx.x * 256 + threadIdx.x;  // 10485760 float4s
  const float* src; bf16_t* dst; int off;
  if (i < 2097152)      { src = hid; dst = oh; off = i; }
  else if (i < 6291456) { src = wq;  dst = oq; off = i - 2097152; }
  else if (i < 8388608) { src = wzp; dst = oz; off = i - 6291456; }
  else                  { src = wo;  dst = oo; off = i - 8388608; }
  const float4 f = ((const float4*)src)[off];
  bf16x4 r;
  r[0] = (bf16_t)f.x; r[1] = (bf16_t)f.y; r[2] = (bf16_t)f.z; r[3] = (bf16_t)f.w;
  ((bf16x4*)dst)[off] = r;
}

// W_b rows 0..31, W_a rows 32..63, zeros 64..127
__global__ __launch_bounds__(256) void k_build_wba(const float* __restrict__ wb,
                                                   const float* __restrict__ wa,
                                                   bf16_t* __restrict__ out) {
  int i = blockIdx.x * 256 + threadIdx.x;
  int e = i * 4;
  int row = e >> 11;
  int col = e & 2047;
  float4 f = make_float4(0.f, 0.f, 0.f, 0.f);
  if (row < 32)      f = *(const float4*)&wb[row * 2048 + col];
  else if (row < 64) f = *(const float4*)&wa[(row - 32) * 2048 + col];
  bf16x4 r;
  r[0] = (bf16_t)f.x; r[1] = (bf16_t)f.y; r[2] = (bf16_t)f.z; r[3] = (bf16_t)f.w;
  *(bf16x4*)&out[e] = r;
}

// ---------------------------------------------------------------- fused projection GEMM
// C = A[4096,2048] @ [Wqkv|Wz|Wba]^T, N=12416 (97 n-tiles x 32 m-tiles).
// Flat grid, m-fastest (id&31) so co-resident blocks share B tiles in L2.
__global__ __launch_bounds__(256) void gemm_fused(const bf16_t* __restrict__ A,
                                                  const bf16_t* __restrict__ Bq,
                                                  const bf16_t* __restrict__ Bz,
                                                  const bf16_t* __restrict__ Bba,
                                                  bf16_t* __restrict__ Cq,
                                                  bf16_t* __restrict__ Cz,
                                                  float* __restrict__ Cba) {
  __shared__ __align__(16) bf16_t As[4096];
  __shared__ __align__(16) bf16_t Bs[4096];
  const int tid  = threadIdx.x;
  const int lane = tid & 63;
  const int wave = tid >> 6;
  const int quad = lane >> 4;
  const int l16  = lane & 15;
  const int wr   = (wave >> 1) * 64;
  const int wc   = (wave & 1) * 64;
  const int mt   = blockIdx.x & 31;
  const int nt   = blockIdx.x >> 5;   // 0..96
  const int m0   = mt * 128;
  const int K    = 2048;
  const int ra   = tid >> 2;
  const int ca   = (tid & 3) * 8;

  const bf16_t* B;
  int nloc;
  if (nt < 64)      { B = Bq;  nloc = nt * 128; }
  else if (nt < 96) { B = Bz;  nloc = (nt - 64) * 128; }
  else              { B = Bba; nloc = 0; }

  const bf16_t* gA = A + (size_t)(m0 + ra) * K + ca;
  const bf16_t* gB = B + (size_t)(nloc + ra) * K + ca;
  bf16_t* lA = &As[tid * 8];
  bf16_t* lB = &Bs[tid * 8];

  floatx4 acc[4][4] = {};

  for (int k0 = 0; k0 < K; k0 += 32) {
    __syncthreads();
    async16(gA + k0, lA);
    async16(gA + k0 + (size_t)64 * K, lA + 2048);
    async16(gB + k0, lB);
    async16(gB + k0 + (size_t)64 * K, lB + 2048);
    __syncthreads();
    bf16x8 af[4], bfr[4];
#pragma unroll
    for (int i = 0; i < 4; ++i) {
      af[i]  = *(const bf16x8*)&As[(wr + i * 16 + l16) * 32 + quad * 8];
      bfr[i] = *(const bf16x8*)&Bs[(wc + i * 16 + l16) * 32 + quad * 8];
    }
#pragma unroll
    for (int mi = 0; mi < 4; ++mi)
#pragma unroll
      for (int ni = 0; ni < 4; ++ni)
        acc[mi][ni] = MFMA16(af[mi], bfr[ni], acc[mi][ni]);
  }

#pragma unroll
  for (int mi = 0; mi < 4; ++mi) {
#pragma unroll
    for (int ni = 0; ni < 4; ++ni) {
      const int row = m0 + wr + mi * 16 + quad * 4;
      const int cl = nloc + wc + ni * 16 + l16;
#pragma unroll
      for (int r = 0; r < 4; ++r) {
        if (nt < 64)      Cq[(size_t)(row + r) * 8192 + cl] = (bf16_t)acc[mi][ni][r];
        else if (nt < 96) Cz[(size_t)(row + r) * 4096 + cl] = (bf16_t)acc[mi][ni][r];
        else              Cba[(size_t)(row + r) * 128 + cl] = acc[mi][ni][r];
      }
    }
  }
}

// ---------------------------------------------------------------- out GEMM (flat, m-fast)
__global__ __launch_bounds__(256) void gemm_out(const bf16_t* __restrict__ A,
                                                const bf16_t* __restrict__ B,
                                                float* __restrict__ C,
                                                int N, int K) {
  __shared__ __align__(16) bf16_t As[4096];
  __shared__ __align__(16) bf16_t Bs[4096];
  const int tid  = threadIdx.x;
  const int lane = tid & 63;
  const int wave = tid >> 6;
  const int quad = lane >> 4;
  const int l16  = lane & 15;
  const int wr   = (wave >> 1) * 64;
  const int wc   = (wave & 1) * 64;
  const int m0   = (blockIdx.x & 31) * 128;
  const int n0   = (blockIdx.x >> 5) * 128;
  const int ra   = tid >> 2;
  const int ca   = (tid & 3) * 8;

  const bf16_t* gA = A + (size_t)(m0 + ra) * K + ca;
  const bf16_t* gB = B + (size_t)(n0 + ra) * K + ca;
  bf16_t* lA = &As[tid * 8];
  bf16_t* lB = &Bs[tid * 8];

  floatx4 acc[4][4] = {};

  for (int k0 = 0; k0 < K; k0 += 32) {
    __syncthreads();
    async16(gA + k0, lA);
    async16(gA + k0 + (size_t)64 * K, lA + 2048);
    async16(gB + k0, lB);
    async16(gB + k0 + (size_t)64 * K, lB + 2048);
    __syncthreads();
    bf16x8 af[4], bfr[4];
#pragma unroll
    for (int i = 0; i < 4; ++i) {
      af[i]  = *(const bf16x8*)&As[(wr + i * 16 + l16) * 32 + quad * 8];
      bfr[i] = *(const bf16x8*)&Bs[(wc + i * 16 + l16) * 32 + quad * 8];
    }
#pragma unroll
    for (int mi = 0; mi < 4; ++mi)
#pragma unroll
      for (int ni = 0; ni < 4; ++ni)
        acc[mi][ni] = MFMA16(af[mi], bfr[ni], acc[mi][ni]);
  }

#pragma unroll
  for (int mi = 0; mi < 4; ++mi) {
#pragma unroll
    for (int ni = 0; ni < 4; ++ni) {
      const int row = m0 + wr + mi * 16 + quad * 4;
      const int col = n0 + wc + ni * 16 + l16;
#pragma unroll
      for (int r = 0; r < 4; ++r)
        C[(size_t)(row + r) * N + col] = acc[mi][ni][r];
    }
  }
}

// ---------------------------------------------------------------- beta / g ([h][t] layout)
__global__ __launch_bounds__(256) void k_betag(const float* __restrict__ cba,
                                               const float* __restrict__ A_log,
                                               const float* __restrict__ dtb,
                                               float* __restrict__ beta_t,
                                               float* __restrict__ g_t) {
  int i = blockIdx.x * 256 + threadIdx.x;  // T*32
  int t = i >> 5, h = i & 31;
  float b = cba[t * 128 + h];
  float a = cba[t * 128 + 32 + h];
  beta_t[h * 4096 + t] = 1.f / (1.f + __expf(-b));
  float x = a + dtb[h];
  float sp = (x > 20.f) ? x : log1pf(__expf(x));
  g_t[h * 4096 + t] = -__expf(A_log[h]) * sp;
}

// ---------------------------------------------------------------- conv4 + silu + l2norm
__global__ __launch_bounds__(64) void k_conv(const bf16_t* __restrict__ mixed,
                                             const float* __restrict__ cw,
                                             bf16_t* __restrict__ qo,
                                             bf16_t* __restrict__ ko,
                                             bf16_t* __restrict__ vo) {
  const int grp = blockIdx.x;
  const int t0 = blockIdx.y * 8;
  const int l = threadIdx.x;
  const int c0 = grp * 128 + l;
  const int c1 = c0 + 64;
  const float4 w0 = *(const float4*)&cw[c0 * 4];
  const float4 w1 = *(const float4*)&cw[c1 * 4];
  float h0[3], h1[3];
#pragma unroll
  for (int j = 0; j < 3; ++j) {
    int tt = t0 - 3 + j;
    h0[j] = (tt >= 0) ? (float)mixed[(size_t)tt * 8192 + c0] : 0.f;
    h1[j] = (tt >= 0) ? (float)mixed[(size_t)tt * 8192 + c1] : 0.f;
  }
#pragma unroll
  for (int i = 0; i < 8; ++i) {
    const int t = t0 + i;
    float x0 = (float)mixed[(size_t)t * 8192 + c0];
    float x1 = (float)mixed[(size_t)t * 8192 + c1];
    float a0 = w0.x * h0[0] + w0.y * h0[1] + w0.z * h0[2] + w0.w * x0;
    float a1 = w1.x * h1[0] + w1.y * h1[1] + w1.z * h1[2] + w1.w * x1;
    h0[0] = h0[1]; h0[1] = h0[2]; h0[2] = x0;
    h1[0] = h1[1]; h1[1] = h1[2]; h1[2] = x1;
    float v0 = siluf(a0), v1 = siluf(a1);
    if (grp < 32) {
      float s = v0 * v0 + v1 * v1;
#pragma unroll
      for (int m = 1; m < 64; m <<= 1) s += __shfl_xor(s, m);
      float r = rsqrtf(s + 1e-6f);
      if (grp < 16) {
        bf16_t* q = qo + ((size_t)t * 16 + grp) * 128;
        q[l]      = (bf16_t)(v0 * r * 0.08838834764831845f);  // DK^-0.5 folded
        q[l + 64] = (bf16_t)(v1 * r * 0.08838834764831845f);
      } else {
        bf16_t* k = ko + ((size_t)t * 16 + grp - 16) * 128;
        k[l]      = (bf16_t)(v0 * r);
        k[l + 64] = (bf16_t)(v1 * r);
      }
    } else {
      bf16_t* v = vo + ((size_t)t * 32 + grp - 32) * 128;
      v[l]      = (bf16_t)v0;
      v[l + 64] = (bf16_t)v1;
    }
  }
}

// ---------------------------------------------------------------- k_prep
// grid = 32 heads x 64 chunks. Solves (I+C)[Vt | W] = [beta*V | beta*A*K];
// writes VtT ([dv][t]), W' = -W ([t][dk]), M, KT2 (= K^T with sc_t folded,
// per v-head), smalls (A).
__global__ __launch_bounds__(256, 2) void k_prep(
    const bf16_t* __restrict__ qg, const bf16_t* __restrict__ kg,
    const bf16_t* __restrict__ vg,
    const float* __restrict__ bb_t, const float* __restrict__ gb_t,
    bf16_t* __restrict__ Vt, bf16_t* __restrict__ Wlo, bf16_t* __restrict__ Whi,
    bf16_t* __restrict__ Mout, bf16_t* __restrict__ kt2, float* __restrict__ smalls) {
  const int c = blockIdx.x >> 5;
  const int h = blockIdx.x & 31;
  const int kh = h >> 1;
  const int t0 = c * 64;
  const int tid = threadIdx.x, lane = tid & 63, wave = tid >> 6;
  const int quad = lane >> 4, l16 = lane & 15;

  __shared__ __align__(16) bf16_t lsKQ[2][64][136];
  __shared__ float lsC[64][68];
  __shared__ float lsG[64], lsA[64], lsSc[64], lsBeta[64];

  {
    const int r = tid >> 2, s0 = (tid & 3) * 32;
    const bf16_t* kr = kg + ((size_t)(t0 + r) * 16 + kh) * 128 + s0;
    const bf16_t* qr = qg + ((size_t)(t0 + r) * 16 + kh) * 128 + s0;
#pragma unroll
    for (int j = 0; j < 4; ++j) {
      *(uint4*)&lsKQ[0][r][s0 + j * 8] = *(const uint4*)&kr[j * 8];
      *(uint4*)&lsKQ[1][r][s0 + j * 8] = *(const uint4*)&qr[j * 8];
    }
  }
  if (wave == 0) {
    float gv = gb_t[(size_t)h * 4096 + t0 + lane];
#pragma unroll
    for (int off = 1; off < 64; off <<= 1) {
      float n = __shfl_up(gv, off);
      if (lane >= off) gv += n;
    }
    float GL = __shfl(gv, 63);
    lsG[lane] = gv;
    lsA[lane] = __expf(gv);
    lsSc[lane] = __expf(GL - gv);
    lsBeta[lane] = bb_t[(size_t)h * 4096 + t0 + lane];
  }
  __syncthreads();

  const int mr = (wave >> 1) * 32, nr = (wave & 1) * 32;
  floatx4 ak[2][2] = {}, aq[2][2] = {};
  if (wave != 1) {
#pragma unroll
    for (int ks = 0; ks < 4; ++ks) {
      bf16x8 yf[2], xk[2], xq[2];
#pragma unroll
      for (int i = 0; i < 2; ++i) {
        yf[i] = *(const bf16x8*)&lsKQ[0][nr + i * 16 + l16][ks * 32 + quad * 8];
        xk[i] = *(const bf16x8*)&lsKQ[0][mr + i * 16 + l16][ks * 32 + quad * 8];
        xq[i] = *(const bf16x8*)&lsKQ[1][mr + i * 16 + l16][ks * 32 + quad * 8];
      }
#pragma unroll
      for (int i = 0; i < 2; ++i)
#pragma unroll
        for (int j = 0; j < 2; ++j) {
          ak[i][j] = MFMA16(xk[i], yf[j], ak[i][j]);
          aq[i][j] = MFMA16(xq[i], yf[j], aq[i][j]);
        }
    }
  }
  bf16_t* Mb = Mout + (size_t)(h * 64 + c) * 4096;
#pragma unroll
  for (int i = 0; i < 2; ++i)
#pragma unroll
    for (int j = 0; j < 2; ++j)
#pragma unroll
      for (int r = 0; r < 4; ++r) {
        int t = mr + i * 16 + quad * 4 + r;
        int s = nr + j * 16 + l16;
        float e = __expf(lsG[t] - lsG[s]);
        float cv = (s < t) ? lsBeta[t] * e * ak[i][j][r] : 0.f;
        float mv = (s <= t) ? e * aq[i][j][r] : 0.f;
        if (wave != 1) lsC[t][s] = cv;
        Mb[t * 64 + s] = (bf16_t)mv;
      }
  __syncthreads();

  // forward substitution: thread <-> column. cols 0..127: V, 128..255: W-rhs
  const int col = tid & 127;
  const bool isW = tid >= 128;
  float vals[64];
#pragma unroll
  for (int t = 0; t < 64; ++t) {
    float b;
    if (!isW) b = (float)vg[((size_t)(t0 + t) * 32 + h) * 128 + col];
    else      b = lsA[t] * (float)lsKQ[0][t][col];
    vals[t] = lsBeta[t] * b;
  }
#pragma unroll
  for (int t = 1; t < 64; ++t) {
    float acc = vals[t];
#pragma unroll
    for (int s4 = 0; s4 <= (t - 1) >> 2; ++s4) {
      float4 cv = *(const float4*)&lsC[t][s4 * 4];
      acc -= cv.x * vals[s4 * 4 + 0];
      acc -= cv.y * vals[s4 * 4 + 1];
      acc -= cv.z * vals[s4 * 4 + 2];
      acc -= cv.w * vals[s4 * 4 + 3];
    }
    vals[t] = acc;
  }

  // V columns: direct transposed write (VtT[dv][t])
  if (!isW) {
    bf16_t* vd = Vt + (size_t)(h * 64 + c) * 8192 + (size_t)col * 64;
#pragma unroll
    for (int j = 0; j < 16; ++j) {
      bf16x4 p;
      p[0] = (bf16_t)vals[j * 4 + 0];
      p[1] = (bf16_t)vals[j * 4 + 1];
      p[2] = (bf16_t)vals[j * 4 + 2];
      p[3] = (bf16_t)vals[j * 4 + 3];
      *(bf16x4*)&vd[j * 4] = p;
    }
  } else {
#pragma unroll
    for (int t = 0; t < 64; ++t) vals[t] = -vals[t];  // W' = -W
  }

  // KT2 = K^T with sc_t folded, per v-head: [dk 128][t 64]
  {
    const int dk = tid >> 1, sh = (tid & 1) * 32;
    bf16_t* kd = kt2 + ((size_t)h * 64 + c) * 8192 + (size_t)dk * 64 + sh;
#pragma unroll
    for (int j4 = 0; j4 < 4; ++j4) {
      bf16x8 v;
#pragma unroll
      for (int e = 0; e < 8; ++e) {
        int t = sh + j4 * 8 + e;
        v[e] = (bf16_t)((float)lsKQ[0][t][dk] * lsSc[t]);
      }
      *(bf16x8*)&kd[j4 * 8] = v;
    }
  }
  if (tid < 64) {
    float* sm = smalls + (size_t)(h * 64 + c) * 128;
    sm[tid] = lsA[tid];
    sm[64 + tid] = lsSc[tid];
  }
  __syncthreads();

  // transpose W half via LDS (overlay lsKQ), pitch 272
  bf16_t* lsT = &lsKQ[0][0][0];
  if (isW) {
#pragma unroll
    for (int t = 0; t < 64; ++t) lsT[t * 272 + tid] = (bf16_t)vals[t];
  }
  __syncthreads();

  // cooperative vectorized W' write: [t][dk 128]
  {
    const int r = tid >> 2, part = tid & 3;
    const bf16_t* src = &lsT[r * 272 + 128 + part * 32];
    bf16_t* Wb = (h < 16 ? Wlo : Whi) + (size_t)((h & 15) * 64 + c) * 8192 + r * 128 + part * 32;
#pragma unroll
    for (int j = 0; j < 4; ++j)
      *(uint4*)&Wb[j * 8] = *(const uint4*)&src[j * 8];
  }
}

// ---------------------------------------------------------------- chain prefetch
__device__ __forceinline__ void chain_prefetch(
    int c2, int wave, int l16, int quad, int trow, int dv0, int kh,
    const bf16_t* __restrict__ Wbase, const bf16_t* __restrict__ Vbase,
    const bf16_t* __restrict__ Mbase, const bf16_t* __restrict__ qg,
    const bf16_t* __restrict__ Kbase, const float* __restrict__ Sbase,
    bf16x8 nW[4], bf16x8 nQ[4], bf16x8 nK[4], bf16x8 nM[2],
    bf16x4 nV[4], float4& nA, float& nAL) {
  const bf16_t* Wn = Wbase + (size_t)c2 * 8192;
  const bf16_t* Vn = Vbase + (size_t)c2 * 8192;
  const bf16_t* Qn = qg + ((size_t)(c2 * 64 + wave * 16 + l16) * 16 + kh) * 128;
  const bf16_t* Kn = Kbase + (size_t)c2 * 8192;
  const bf16_t* Mn = Mbase + (size_t)c2 * 4096 + (wave * 16 + l16) * 64;
  const float* sm = Sbase + (size_t)c2 * 128;
#pragma unroll
  for (int ks = 0; ks < 4; ++ks) {
    nW[ks] = *(const bf16x8*)&Wn[(size_t)(wave * 16 + l16) * 128 + ks * 32 + quad * 8];
    nQ[ks] = *(const bf16x8*)&Qn[ks * 32 + quad * 8];
    nK[ks] = *(const bf16x8*)&Kn[(size_t)((wave + 4 * (ks >> 1)) * 16 + l16) * 64 + (ks & 1) * 32 + quad * 8];
  }
#pragma unroll
  for (int ks = 0; ks < 2; ++ks) nM[ks] = *(const bf16x8*)&Mn[ks * 32 + quad * 8];
#pragma unroll
  for (int tn = 0; tn < 4; ++tn)
    nV[tn] = *(const bf16x4*)&Vn[(size_t)(dv0 + tn * 16 + l16) * 64 + trow];
  nA = *(const float4*)&sm[trow];
  nAL = sm[63];
}

// ---------------------------------------------------------------- k_chain
// grid = 64: blockIdx = half*32 + h. Per chunk:
// X = Vt + W'.S ; o = A*(Q.S) + M.X ; S' = aL*S + KT2.X (sc pre-folded).
__global__ __launch_bounds__(256, 1) void k_chain(
    const bf16_t* __restrict__ qg, const bf16_t* __restrict__ VtT,
    const bf16_t* __restrict__ Wlo, const bf16_t* __restrict__ Whi,
    const bf16_t* __restrict__ Mg, const bf16_t* __restrict__ kt2,
    const float* __restrict__ smalls, bf16_t* __restrict__ o) {
  const int h = blockIdx.x & 31;
  const int dv0 = (blockIdx.x >> 5) * 64;
  const int kh = h >> 1;
  const int tid = threadIdx.x, lane = tid & 63, wave = tid >> 6;
  const int quad = lane >> 4, l16 = lane & 15;
  const int trow = wave * 16 + quad * 4;

  __shared__ __align__(16) bf16_t lsXT[64][72];
  __shared__ __align__(16) bf16_t lsS[64][136];

  const bf16_t* Wbase = (h < 16 ? Wlo : Whi) + (size_t)(h & 15) * 64 * 8192;
  const bf16_t* Vbase = VtT + (size_t)h * 64 * 8192;
  const bf16_t* Mbase = Mg + (size_t)h * 64 * 4096;
  const bf16_t* Kbase = kt2 + (size_t)h * 64 * 8192;
  const float*  Sbase = smalls + (size_t)h * 64 * 128;

  floatx4 sacc[2][4] = {};
  for (int i = tid; i < 64 * 136; i += 256) (&lsS[0][0])[i] = (bf16_t)0.f;

  bf16x8 nW[4], nQ[4], nK[4], nM[2];
  bf16x4 nV[4];
  float4 nA;
  float nAL;
  chain_prefetch(0, wave, l16, quad, trow, dv0, kh, Wbase, Vbase, Mbase, qg, Kbase,
                 Sbase, nW, nQ, nK, nM, nV, nA, nAL);
  __syncthreads();

  for (int cc = 0; cc < 64; ++cc) {
    const int t0 = cc * 64;
    bf16x8 cW[4], cQ[4], cK[4], cM[2];
    float cV[16];
    float4 cA = nA;
    float cAL = nAL;
#pragma unroll
    for (int ks = 0; ks < 4; ++ks) { cW[ks] = nW[ks]; cQ[ks] = nQ[ks]; cK[ks] = nK[ks]; }
    cM[0] = nM[0]; cM[1] = nM[1];
#pragma unroll
    for (int tn = 0; tn < 4; ++tn)
#pragma unroll
      for (int r = 0; r < 4; ++r) cV[tn * 4 + r] = (float)nV[tn][r];

    if (cc + 1 < 64)
      chain_prefetch(cc + 1, wave, l16, quad, trow, dv0, kh, Wbase, Vbase, Mbase,
                     qg, Kbase, Sbase, nW, nQ, nK, nM, nV, nA, nAL);

    // ---- P0: X = Vt + W'.S  (bS kept for P1's Q.S)
    bf16x8 bS[4][4];
#pragma unroll
    for (int ks = 0; ks < 4; ++ks)
#pragma unroll
      for (int tn = 0; tn < 4; ++tn)
        bS[ks][tn] = *(const bf16x8*)&lsS[tn * 16 + l16][ks * 32 + quad * 8];
    floatx4 xacc[4];
#pragma unroll
    for (int tn = 0; tn < 4; ++tn)
#pragma unroll
      for (int r = 0; r < 4; ++r) xacc[tn][r] = cV[tn * 4 + r];
#pragma unroll
    for (int ks = 0; ks < 4; ++ks)
#pragma unroll
      for (int tn = 0; tn < 4; ++tn)
        xacc[tn] = MFMA16(cW[ks], bS[ks][tn], xacc[tn]);
#pragma unroll
    for (int tn = 0; tn < 4; ++tn) {
      bf16x4 px;
#pragma unroll
      for (int r = 0; r < 4; ++r) px[r] = (bf16_t)xacc[tn][r];
      *(bf16x4*)&lsXT[tn * 16 + l16][trow] = px;
    }
    barrier_lds();  // B1: X ready; lsS reads done

    // ---- P1: load X frags once; o = A*(Q.S) + M.X ; S' = aL*S + KT2.X
    bf16x8 bX[2][4];
#pragma unroll
    for (int ks = 0; ks < 2; ++ks)
#pragma unroll
      for (int tn = 0; tn < 4; ++tn)
        bX[ks][tn] = *(const bf16x8*)&lsXT[tn * 16 + l16][ks * 32 + quad * 8];
    floatx4 qacc[4] = {};
#pragma unroll
    for (int ks = 0; ks < 4; ++ks)
#pragma unroll
      for (int tn = 0; tn < 4; ++tn)
        qacc[tn] = MFMA16(cQ[ks], bS[ks][tn], qacc[tn]);
#pragma unroll
    for (int tn = 0; tn < 4; ++tn)
#pragma unroll
      for (int r = 0; r < 4; ++r) qacc[tn][r] *= ((const float*)&cA)[r];
#pragma unroll
    for (int ks = 0; ks < 2; ++ks)
#pragma unroll
      for (int tn = 0; tn < 4; ++tn)
        qacc[tn] = MFMA16(cM[ks], bX[ks][tn], qacc[tn]);
#pragma unroll
    for (int tn = 0; tn < 4; ++tn)
#pragma unroll
      for (int r = 0; r < 4; ++r)
        o[((size_t)(t0 + trow + r) * 32 + h) * 128 + dv0 + tn * 16 + l16] =
            (bf16_t)qacc[tn][r];
#pragma unroll
    for (int mh = 0; mh < 2; ++mh)
#pragma unroll
      for (int tn = 0; tn < 4; ++tn)
#pragma unroll
        for (int r = 0; r < 4; ++r) sacc[mh][tn][r] *= cAL;
#pragma unroll
    for (int ks = 0; ks < 2; ++ks)
#pragma unroll
      for (int mh = 0; mh < 2; ++mh)
#pragma unroll
        for (int tn = 0; tn < 4; ++tn)
          sacc[mh][tn] = MFMA16(cK[mh * 2 + ks], bX[ks][tn], sacc[mh][tn]);
    // ---- P2: refresh bf16 state (all lsS reads happened before B1)
#pragma unroll
    for (int mh = 0; mh < 2; ++mh)
#pragma unroll
      for (int tn = 0; tn < 4; ++tn) {
        bf16x4 ps;
#pragma unroll
        for (int r = 0; r < 4; ++r) ps[r] = (bf16_t)sacc[mh][tn][r];
        *(bf16x4*)&lsS[tn * 16 + l16][(wave + 4 * mh) * 16 + quad * 4] = ps;
      }
    barrier_lds();  // B2
  }
}

// ---------------------------------------------------------------- RMSNorm * silu(z)
__global__ __launch_bounds__(256) void k_gate(const bf16_t* __restrict__ o,
                                              const bf16_t* __restrict__ z,
                                              const float* __restrict__ nw,
                                              bf16_t* __restrict__ y) {
  const int row = blockIdx.x * 4 + (threadIdx.x >> 6);  // t*32+h
  const int l = threadIdx.x & 63;
  const bf16_t* orow = o + (size_t)row * 128;
  float o0 = (float)orow[l], o1 = (float)orow[l + 64];
  float s = o0 * o0 + o1 * o1;
#pragma unroll
  for (int m = 1; m < 64; m <<= 1) s += __shfl_xor(s, m);
  float r = rsqrtf(s * (1.f / 128.f) + 1e-6f);
  const bf16_t* zrow = z + (size_t)row * 128;
  float z0 = (float)zrow[l], z1 = (float)zrow[l + 64];
  bf16_t* yrow = y + (size_t)row * 128;
  yrow[l]      = (bf16_t)(o0 * r * nw[l] * siluf(z0));
  yrow[l + 64] = (bf16_t)(o1 * r * nw[l + 64] * siluf(z1));
}

// ---------------------------------------------------------------- launch
extern "C" void kernel_launch(void* const* d_in, const int* in_sizes, int n_in,
                              void* d_out, int out_size, void* d_ws, size_t ws_size,
                              hipStream_t stream) {
  const float* hidden = (const float*)d_in[0];
  const float* W_qkv  = (const float*)d_in[1];
  const float* W_z    = (const float*)d_in[2];
  const float* W_b    = (const float*)d_in[3];
  const float* W_a    = (const float*)d_in[4];
  const float* conv_w = (const float*)d_in[5];
  const float* dt_b   = (const float*)d_in[6];
  const float* A_log  = (const float*)d_in[7];
  const float* norm_w = (const float*)d_in[8];
  const float* W_out  = (const float*)d_in[9];
  float* out = (float*)d_out;

  char* w = (char*)d_ws;
  const size_t MB = 1024 * 1024;
  // time-disjoint overlays:
  bf16_t* hs    = (bf16_t*)(w + 0 * MB);     // 16MB -> Wlo (prep out)
  bf16_t* Wlo   = hs;
  bf16_t* wqkv  = (bf16_t*)(w + 16 * MB);    // 32MB -> VtT (prep) -> ybuf (gate)
  bf16_t* Vtb   = wqkv;
  bf16_t* ybuf  = wqkv;
  bf16_t* wz    = (bf16_t*)(w + 48 * MB);    // 16MB -> Whi
  bf16_t* Whi   = wz;
  bf16_t* wout  = (bf16_t*)(w + 64 * MB);    // 16MB (live till end)
  bf16_t* wba   = (bf16_t*)(w + 80 * MB);    // 0.5MB
  bf16_t* mixed = (bf16_t*)(w + 81 * MB);    // 64MB (proj out); after conv:
  bf16_t* kt2b  = (bf16_t*)(w + 81 * MB);    //   KT2 32MB [81,113)
  bf16_t* Mbuf  = (bf16_t*)(w + 113 * MB);   //   M 16MB  [113,129)
  bf16_t* zbuf  = (bf16_t*)(w + 145 * MB);   // 32MB (live till gate)
  float*  cba   = (float*)(w + 177 * MB);    // 2MB -> smalls
  float*  smalls= cba;
  bf16_t* qb    = (bf16_t*)(w + 179 * MB);   // 16MB (live till chain)
  bf16_t* kb    = (bf16_t*)(w + 195 * MB);   // 16MB (prep in)
  bf16_t* vb    = (bf16_t*)(w + 211 * MB);   // 32MB (prep in) -> obuf (chain out)
  bf16_t* obuf  = vb;
  float*  betab = (float*)(w + 243 * MB);    // 0.5MB [h][t]
  float*  gbuf  = (float*)(w + 243 * MB + 512 * 1024);  // 0.5MB [h][t]

  k_cvt_all<<<40960, 256, 0, stream>>>(hidden, W_qkv, W_z, W_out, hs, wqkv, wz, wout);
  k_build_wba<<<256, 256, 0, stream>>>(W_b, W_a, wba);

  gemm_fused<<<3104, 256, 0, stream>>>(hs, wqkv, wz, wba, mixed, zbuf, cba);
  k_betag<<<512, 256, 0, stream>>>(cba, A_log, dt_b, betab, gbuf);

  k_conv<<<dim3(64, 512), 64, 0, stream>>>(mixed, conv_w, qb, kb, vb);

  k_prep<<<2048, 256, 0, stream>>>(qb, kb, vb, betab, gbuf,
                                   Vtb, Wlo, Whi, Mbuf, kt2b, smalls);
  k_chain<<<64, 256, 0, stream>>>(qb, Vtb, Wlo, Whi, Mbuf, kt2b, smalls, obuf);

  k_gate<<<32768, 256, 0, stream>>>(obuf, zbuf, norm_w, ybuf);
  gemm_out<<<512, 256, 0, stream>>>(ybuf, wout, out, 2048, 4096);
}

// Round 6
// 999.436 us; speedup vs baseline: 1.0027x; 1.0027x over previous
//
#include <hip/hip_runtime.h>
#include <cstdint>
#include <cstddef>

typedef __bf16 bf16_t;
typedef __bf16 bf16x8 __attribute__((ext_vector_type(8)));
typedef __bf16 bf16x4 __attribute__((ext_vector_type(4)));
typedef float floatx4 __attribute__((ext_vector_type(4)));

// ---------------------------------------------------------------- helpers
__device__ __forceinline__ void async16(const bf16_t* g, bf16_t* l) {
  __builtin_amdgcn_global_load_lds(
      (const __attribute__((address_space(1))) unsigned int*)g,
      (__attribute__((address_space(3))) unsigned int*)l, 16, 0, 0);
}

// Barrier draining ONLY lgkmcnt — keeps prefetch global loads in flight.
__device__ __forceinline__ void barrier_lds() {
  asm volatile("s_waitcnt lgkmcnt(0)\n\ts_barrier" ::: "memory");
}

__device__ __forceinline__ float siluf(float x) { return x / (1.f + __expf(-x)); }

#define MFMA16(a, b, c) __builtin_amdgcn_mfma_f32_16x16x32_bf16(a, b, c, 0, 0, 0)

// ---------------------------------------------------------------- fp32 -> bf16 (all 4 tensors)
__global__ __launch_bounds__(256) void k_cvt_all(const float* __restrict__ hid,
                                                 const float* __restrict__ wq,
                                                 const float* __restrict__ wzp,
                                                 const float* __restrict__ wo,
                                                 bf16_t* __restrict__ oh,
                                                 bf16_t* __restrict__ oq,
                                                 bf16_t* __restrict__ oz,
                                                 bf16_t* __restrict__ oo) {
  int i = blockIdx.x * 256 + threadIdx.x;  // 10485760 float4s
  const float* src; bf16_t* dst; int off;
  if (i < 2097152)      { src = hid; dst = oh; off = i; }
  else if (i < 6291456) { src = wq;  dst = oq; off = i - 2097152; }
  else if (i < 8388608) { src = wzp; dst = oz; off = i - 6291456; }
  else                  { src = wo;  dst = oo; off = i - 8388608; }
  const float4 f = ((const float4*)src)[off];
  bf16x4 r;
  r[0] = (bf16_t)f.x; r[1] = (bf16_t)f.y; r[2] = (bf16_t)f.z; r[3] = (bf16_t)f.w;
  ((bf16x4*)dst)[off] = r;
}

// W_b rows 0..31, W_a rows 32..63, zeros 64..127
__global__ __launch_bounds__(256) void k_build_wba(const float* __restrict__ wb,
                                                   const float* __restrict__ wa,
                                                   bf16_t* __restrict__ out) {
  int i = blockIdx.x * 256 + threadIdx.x;
  int e = i * 4;
  int row = e >> 11;
  int col = e & 2047;
  float4 f = make_float4(0.f, 0.f, 0.f, 0.f);
  if (row < 32)      f = *(const float4*)&wb[row * 2048 + col];
  else if (row < 64) f = *(const float4*)&wa[(row - 32) * 2048 + col];
  bf16x4 r;
  r[0] = (bf16_t)f.x; r[1] = (bf16_t)f.y; r[2] = (bf16_t)f.z; r[3] = (bf16_t)f.w;
  *(bf16x4*)&out[e] = r;
}

// ---------------------------------------------------------------- fused projection GEMM
// C = A[4096,2048] @ [Wqkv|Wz|Wba]^T. grid dim3(97,32): x = n-tile (FASTEST,
// A-tile-stationary in L2 — measured-good order), y = m-tile.
__global__ __launch_bounds__(256) void gemm_fused(const bf16_t* __restrict__ A,
                                                  const bf16_t* __restrict__ Bq,
                                                  const bf16_t* __restrict__ Bz,
                                                  const bf16_t* __restrict__ Bba,
                                                  bf16_t* __restrict__ Cq,
                                                  bf16_t* __restrict__ Cz,
                                                  float* __restrict__ Cba) {
  __shared__ __align__(16) bf16_t As[4096];
  __shared__ __align__(16) bf16_t Bs[4096];
  const int tid  = threadIdx.x;
  const int lane = tid & 63;
  const int wave = tid >> 6;
  const int quad = lane >> 4;
  const int l16  = lane & 15;
  const int wr   = (wave >> 1) * 64;
  const int wc   = (wave & 1) * 64;
  const int nt   = blockIdx.x;        // 0..96 (fastest)
  const int m0   = blockIdx.y * 128;
  const int K    = 2048;
  const int ra   = tid >> 2;
  const int ca   = (tid & 3) * 8;

  const bf16_t* B;
  int nloc, ostr;
  bf16_t* c16 = nullptr;
  float* c32 = nullptr;
  if (nt < 64)      { B = Bq;  nloc = nt * 128;        c16 = Cq; ostr = 8192; }
  else if (nt < 96) { B = Bz;  nloc = (nt - 64) * 128; c16 = Cz; ostr = 4096; }
  else              { B = Bba; nloc = 0;               c32 = Cba; ostr = 128; }

  const bf16_t* gA = A + (size_t)(m0 + ra) * K + ca;
  const bf16_t* gB = B + (size_t)(nloc + ra) * K + ca;
  bf16_t* lA = &As[tid * 8];
  bf16_t* lB = &Bs[tid * 8];

  floatx4 acc[4][4] = {};

  for (int k0 = 0; k0 < K; k0 += 32) {
    __syncthreads();
    async16(gA + k0, lA);
    async16(gA + k0 + (size_t)64 * K, lA + 2048);
    async16(gB + k0, lB);
    async16(gB + k0 + (size_t)64 * K, lB + 2048);
    __syncthreads();
    bf16x8 af[4], bfr[4];
#pragma unroll
    for (int i = 0; i < 4; ++i) {
      af[i]  = *(const bf16x8*)&As[(wr + i * 16 + l16) * 32 + quad * 8];
      bfr[i] = *(const bf16x8*)&Bs[(wc + i * 16 + l16) * 32 + quad * 8];
    }
#pragma unroll
    for (int mi = 0; mi < 4; ++mi)
#pragma unroll
      for (int ni = 0; ni < 4; ++ni)
        acc[mi][ni] = MFMA16(af[mi], bfr[ni], acc[mi][ni]);
  }

#pragma unroll
  for (int mi = 0; mi < 4; ++mi) {
#pragma unroll
    for (int ni = 0; ni < 4; ++ni) {
      const int row = m0 + wr + mi * 16 + quad * 4;
      const int cl = nloc + wc + ni * 16 + l16;
#pragma unroll
      for (int r = 0; r < 4; ++r) {
        if (c32) c32[(size_t)(row + r) * ostr + cl] = acc[mi][ni][r];
        else     c16[(size_t)(row + r) * ostr + cl] = (bf16_t)acc[mi][ni][r];
      }
    }
  }
}

// ---------------------------------------------------------------- out GEMM (n-fastest 2D grid)
__global__ __launch_bounds__(256) void gemm_out(const bf16_t* __restrict__ A,
                                                const bf16_t* __restrict__ B,
                                                float* __restrict__ C,
                                                int N, int K) {
  __shared__ __align__(16) bf16_t As[4096];
  __shared__ __align__(16) bf16_t Bs[4096];
  const int tid  = threadIdx.x;
  const int lane = tid & 63;
  const int wave = tid >> 6;
  const int quad = lane >> 4;
  const int l16  = lane & 15;
  const int wr   = (wave >> 1) * 64;
  const int wc   = (wave & 1) * 64;
  const int m0   = blockIdx.y * 128;
  const int n0   = blockIdx.x * 128;
  const int ra   = tid >> 2;
  const int ca   = (tid & 3) * 8;

  const bf16_t* gA = A + (size_t)(m0 + ra) * K + ca;
  const bf16_t* gB = B + (size_t)(n0 + ra) * K + ca;
  bf16_t* lA = &As[tid * 8];
  bf16_t* lB = &Bs[tid * 8];

  floatx4 acc[4][4] = {};

  for (int k0 = 0; k0 < K; k0 += 32) {
    __syncthreads();
    async16(gA + k0, lA);
    async16(gA + k0 + (size_t)64 * K, lA + 2048);
    async16(gB + k0, lB);
    async16(gB + k0 + (size_t)64 * K, lB + 2048);
    __syncthreads();
    bf16x8 af[4], bfr[4];
#pragma unroll
    for (int i = 0; i < 4; ++i) {
      af[i]  = *(const bf16x8*)&As[(wr + i * 16 + l16) * 32 + quad * 8];
      bfr[i] = *(const bf16x8*)&Bs[(wc + i * 16 + l16) * 32 + quad * 8];
    }
#pragma unroll
    for (int mi = 0; mi < 4; ++mi)
#pragma unroll
      for (int ni = 0; ni < 4; ++ni)
        acc[mi][ni] = MFMA16(af[mi], bfr[ni], acc[mi][ni]);
  }

#pragma unroll
  for (int mi = 0; mi < 4; ++mi) {
#pragma unroll
    for (int ni = 0; ni < 4; ++ni) {
      const int row = m0 + wr + mi * 16 + quad * 4;
      const int col = n0 + wc + ni * 16 + l16;
#pragma unroll
      for (int r = 0; r < 4; ++r)
        C[(size_t)(row + r) * N + col] = acc[mi][ni][r];
    }
  }
}

// ---------------------------------------------------------------- beta / g ([h][t] layout)
__global__ __launch_bounds__(256) void k_betag(const float* __restrict__ cba,
                                               const float* __restrict__ A_log,
                                               const float* __restrict__ dtb,
                                               float* __restrict__ beta_t,
                                               float* __restrict__ g_t) {
  int i = blockIdx.x * 256 + threadIdx.x;  // T*32
  int t = i >> 5, h = i & 31;
  float b = cba[t * 128 + h];
  float a = cba[t * 128 + 32 + h];
  beta_t[h * 4096 + t] = 1.f / (1.f + __expf(-b));
  float x = a + dtb[h];
  float sp = (x > 20.f) ? x : log1pf(__expf(x));
  g_t[h * 4096 + t] = -__expf(A_log[h]) * sp;
}

// ---------------------------------------------------------------- conv4 + silu + l2norm
__global__ __launch_bounds__(64) void k_conv(const bf16_t* __restrict__ mixed,
                                             const float* __restrict__ cw,
                                             bf16_t* __restrict__ qo,
                                             bf16_t* __restrict__ ko,
                                             bf16_t* __restrict__ vo) {
  const int grp = blockIdx.x;
  const int t0 = blockIdx.y * 8;
  const int l = threadIdx.x;
  const int c0 = grp * 128 + l;
  const int c1 = c0 + 64;
  const float4 w0 = *(const float4*)&cw[c0 * 4];
  const float4 w1 = *(const float4*)&cw[c1 * 4];
  float h0[3], h1[3];
#pragma unroll
  for (int j = 0; j < 3; ++j) {
    int tt = t0 - 3 + j;
    h0[j] = (tt >= 0) ? (float)mixed[(size_t)tt * 8192 + c0] : 0.f;
    h1[j] = (tt >= 0) ? (float)mixed[(size_t)tt * 8192 + c1] : 0.f;
  }
#pragma unroll
  for (int i = 0; i < 8; ++i) {
    const int t = t0 + i;
    float x0 = (float)mixed[(size_t)t * 8192 + c0];
    float x1 = (float)mixed[(size_t)t * 8192 + c1];
    float a0 = w0.x * h0[0] + w0.y * h0[1] + w0.z * h0[2] + w0.w * x0;
    float a1 = w1.x * h1[0] + w1.y * h1[1] + w1.z * h1[2] + w1.w * x1;
    h0[0] = h0[1]; h0[1] = h0[2]; h0[2] = x0;
    h1[0] = h1[1]; h1[1] = h1[2]; h1[2] = x1;
    float v0 = siluf(a0), v1 = siluf(a1);
    if (grp < 32) {
      float s = v0 * v0 + v1 * v1;
#pragma unroll
      for (int m = 1; m < 64; m <<= 1) s += __shfl_xor(s, m);
      float r = rsqrtf(s + 1e-6f);
      if (grp < 16) {
        bf16_t* q = qo + ((size_t)t * 16 + grp) * 128;
        q[l]      = (bf16_t)(v0 * r * 0.08838834764831845f);  // DK^-0.5 folded
        q[l + 64] = (bf16_t)(v1 * r * 0.08838834764831845f);
      } else {
        bf16_t* k = ko + ((size_t)t * 16 + grp - 16) * 128;
        k[l]      = (bf16_t)(v0 * r);
        k[l + 64] = (bf16_t)(v1 * r);
      }
    } else {
      bf16_t* v = vo + ((size_t)t * 32 + grp - 32) * 128;
      v[l]      = (bf16_t)v0;
      v[l + 64] = (bf16_t)v1;
    }
  }
}

// ---------------------------------------------------------------- k_prep
// grid = 32 heads x 64 chunks. Solves (I+C)[Vt | W] = [beta*V | beta*A*K];
// writes VtT ([dv][t]), W' = -W ([t][dk]), M, KT2 (= K^T with sc_t folded,
// per v-head), smalls (A).
__global__ __launch_bounds__(256, 2) void k_prep(
    const bf16_t* __restrict__ qg, const bf16_t* __restrict__ kg,
    const bf16_t* __restrict__ vg,
    const float* __restrict__ bb_t, const float* __restrict__ gb_t,
    bf16_t* __restrict__ Vt, bf16_t* __restrict__ Wlo, bf16_t* __restrict__ Whi,
    bf16_t* __restrict__ Mout, bf16_t* __restrict__ kt2, float* __restrict__ smalls) {
  const int c = blockIdx.x >> 5;
  const int h = blockIdx.x & 31;
  const int kh = h >> 1;
  const int t0 = c * 64;
  const int tid = threadIdx.x, lane = tid & 63, wave = tid >> 6;
  const int quad = lane >> 4, l16 = lane & 15;

  __shared__ __align__(16) bf16_t lsKQ[2][64][136];
  __shared__ float lsC[64][68];
  __shared__ float lsG[64], lsA[64], lsSc[64], lsBeta[64];

  {
    const int r = tid >> 2, s0 = (tid & 3) * 32;
    const bf16_t* kr = kg + ((size_t)(t0 + r) * 16 + kh) * 128 + s0;
    const bf16_t* qr = qg + ((size_t)(t0 + r) * 16 + kh) * 128 + s0;
#pragma unroll
    for (int j = 0; j < 4; ++j) {
      *(uint4*)&lsKQ[0][r][s0 + j * 8] = *(const uint4*)&kr[j * 8];
      *(uint4*)&lsKQ[1][r][s0 + j * 8] = *(const uint4*)&qr[j * 8];
    }
  }
  if (wave == 0) {
    float gv = gb_t[(size_t)h * 4096 + t0 + lane];
#pragma unroll
    for (int off = 1; off < 64; off <<= 1) {
      float n = __shfl_up(gv, off);
      if (lane >= off) gv += n;
    }
    float GL = __shfl(gv, 63);
    lsG[lane] = gv;
    lsA[lane] = __expf(gv);
    lsSc[lane] = __expf(GL - gv);
    lsBeta[lane] = bb_t[(size_t)h * 4096 + t0 + lane];
  }
  __syncthreads();

  const int mr = (wave >> 1) * 32, nr = (wave & 1) * 32;
  floatx4 ak[2][2] = {}, aq[2][2] = {};
  if (wave != 1) {
#pragma unroll
    for (int ks = 0; ks < 4; ++ks) {
      bf16x8 yf[2], xk[2], xq[2];
#pragma unroll
      for (int i = 0; i < 2; ++i) {
        yf[i] = *(const bf16x8*)&lsKQ[0][nr + i * 16 + l16][ks * 32 + quad * 8];
        xk[i] = *(const bf16x8*)&lsKQ[0][mr + i * 16 + l16][ks * 32 + quad * 8];
        xq[i] = *(const bf16x8*)&lsKQ[1][mr + i * 16 + l16][ks * 32 + quad * 8];
      }
#pragma unroll
      for (int i = 0; i < 2; ++i)
#pragma unroll
        for (int j = 0; j < 2; ++j) {
          ak[i][j] = MFMA16(xk[i], yf[j], ak[i][j]);
          aq[i][j] = MFMA16(xq[i], yf[j], aq[i][j]);
        }
    }
  }
  bf16_t* Mb = Mout + (size_t)(h * 64 + c) * 4096;
#pragma unroll
  for (int i = 0; i < 2; ++i)
#pragma unroll
    for (int j = 0; j < 2; ++j)
#pragma unroll
      for (int r = 0; r < 4; ++r) {
        int t = mr + i * 16 + quad * 4 + r;
        int s = nr + j * 16 + l16;
        float e = __expf(lsG[t] - lsG[s]);
        float cv = (s < t) ? lsBeta[t] * e * ak[i][j][r] : 0.f;
        float mv = (s <= t) ? e * aq[i][j][r] : 0.f;
        if (wave != 1) lsC[t][s] = cv;
        Mb[t * 64 + s] = (bf16_t)mv;
      }
  __syncthreads();

  // forward substitution: thread <-> column. cols 0..127: V, 128..255: W-rhs
  const int col = tid & 127;
  const bool isW = tid >= 128;
  float vals[64];
#pragma unroll
  for (int t = 0; t < 64; ++t) {
    float b;
    if (!isW) b = (float)vg[((size_t)(t0 + t) * 32 + h) * 128 + col];
    else      b = lsA[t] * (float)lsKQ[0][t][col];
    vals[t] = lsBeta[t] * b;
  }
#pragma unroll
  for (int t = 1; t < 64; ++t) {
    float acc = vals[t];
#pragma unroll
    for (int s4 = 0; s4 <= (t - 1) >> 2; ++s4) {
      float4 cv = *(const float4*)&lsC[t][s4 * 4];
      acc -= cv.x * vals[s4 * 4 + 0];
      acc -= cv.y * vals[s4 * 4 + 1];
      acc -= cv.z * vals[s4 * 4 + 2];
      acc -= cv.w * vals[s4 * 4 + 3];
    }
    vals[t] = acc;
  }

  // V columns: direct transposed write (VtT[dv][t])
  if (!isW) {
    bf16_t* vd = Vt + (size_t)(h * 64 + c) * 8192 + (size_t)col * 64;
#pragma unroll
    for (int j = 0; j < 16; ++j) {
      bf16x4 p;
      p[0] = (bf16_t)vals[j * 4 + 0];
      p[1] = (bf16_t)vals[j * 4 + 1];
      p[2] = (bf16_t)vals[j * 4 + 2];
      p[3] = (bf16_t)vals[j * 4 + 3];
      *(bf16x4*)&vd[j * 4] = p;
    }
  } else {
#pragma unroll
    for (int t = 0; t < 64; ++t) vals[t] = -vals[t];  // W' = -W
  }

  // KT2 = K^T with sc_t folded, per v-head: [dk 128][t 64]
  {
    const int dk = tid >> 1, sh = (tid & 1) * 32;
    bf16_t* kd = kt2 + ((size_t)h * 64 + c) * 8192 + (size_t)dk * 64 + sh;
#pragma unroll
    for (int j4 = 0; j4 < 4; ++j4) {
      bf16x8 v;
#pragma unroll
      for (int e = 0; e < 8; ++e) {
        int t = sh + j4 * 8 + e;
        v[e] = (bf16_t)((float)lsKQ[0][t][dk] * lsSc[t]);
      }
      *(bf16x8*)&kd[j4 * 8] = v;
    }
  }
  if (tid < 64) {
    float* sm = smalls + (size_t)(h * 64 + c) * 128;
    sm[tid] = lsA[tid];
    sm[64 + tid] = lsSc[tid];
  }
  __syncthreads();

  // transpose W half via LDS (overlay lsKQ), pitch 272
  bf16_t* lsT = &lsKQ[0][0][0];
  if (isW) {
#pragma unroll
    for (int t = 0; t < 64; ++t) lsT[t * 272 + tid] = (bf16_t)vals[t];
  }
  __syncthreads();

  // cooperative vectorized W' write: [t][dk 128]
  {
    const int r = tid >> 2, part = tid & 3;
    const bf16_t* src = &lsT[r * 272 + 128 + part * 32];
    bf16_t* Wb = (h < 16 ? Wlo : Whi) + (size_t)((h & 15) * 64 + c) * 8192 + r * 128 + part * 32;
#pragma unroll
    for (int j = 0; j < 4; ++j)
      *(uint4*)&Wb[j * 8] = *(const uint4*)&src[j * 8];
  }
}

// ---------------------------------------------------------------- chain prefetch (dv=32 slice)
__device__ __forceinline__ void chain_prefetch(
    int c2, int wave, int l16, int quad, int trow, int dv0, int kh,
    const bf16_t* __restrict__ Wbase, const bf16_t* __restrict__ Vbase,
    const bf16_t* __restrict__ Mbase, const bf16_t* __restrict__ qg,
    const bf16_t* __restrict__ Kbase, const float* __restrict__ Sbase,
    bf16x8 nW[4], bf16x8 nQ[4], bf16x8 nK[4], bf16x8 nM[2],
    bf16x4 nV[2], float4& nA, float& nAL) {
  const bf16_t* Wn = Wbase + (size_t)c2 * 8192;
  const bf16_t* Vn = Vbase + (size_t)c2 * 8192;
  const bf16_t* Qn = qg + ((size_t)(c2 * 64 + wave * 16 + l16) * 16 + kh) * 128;
  const bf16_t* Kn = Kbase + (size_t)c2 * 8192;
  const bf16_t* Mn = Mbase + (size_t)c2 * 4096 + (wave * 16 + l16) * 64;
  const float* sm = Sbase + (size_t)c2 * 128;
#pragma unroll
  for (int ks = 0; ks < 4; ++ks) {
    nW[ks] = *(const bf16x8*)&Wn[(size_t)(wave * 16 + l16) * 128 + ks * 32 + quad * 8];
    nQ[ks] = *(const bf16x8*)&Qn[ks * 32 + quad * 8];
    nK[ks] = *(const bf16x8*)&Kn[(size_t)((wave + 4 * (ks >> 1)) * 16 + l16) * 64 + (ks & 1) * 32 + quad * 8];
  }
#pragma unroll
  for (int ks = 0; ks < 2; ++ks) nM[ks] = *(const bf16x8*)&Mn[ks * 32 + quad * 8];
#pragma unroll
  for (int tn = 0; tn < 2; ++tn)
    nV[tn] = *(const bf16x4*)&Vn[(size_t)(dv0 + tn * 16 + l16) * 64 + trow];
  nA = *(const float4*)&sm[trow];
  nAL = sm[63];
}

// ---------------------------------------------------------------- k_chain
// grid = 128: blockIdx = slice*32 + h, slice = dv quarter (32 cols).
// Per chunk: X = Vt + W'.S ; o = A*(Q.S) + M.X ; S' = aL*S + KT2.X.
// Everything slices cleanly by dv; W'/Q/M/KT2 shared reads (L3-served).
__global__ __launch_bounds__(256, 1) void k_chain(
    const bf16_t* __restrict__ qg, const bf16_t* __restrict__ VtT,
    const bf16_t* __restrict__ Wlo, const bf16_t* __restrict__ Whi,
    const bf16_t* __restrict__ Mg, const bf16_t* __restrict__ kt2,
    const float* __restrict__ smalls, bf16_t* __restrict__ o) {
  const int h = blockIdx.x & 31;
  const int dv0 = (blockIdx.x >> 5) * 32;
  const int kh = h >> 1;
  const int tid = threadIdx.x, lane = tid & 63, wave = tid >> 6;
  const int quad = lane >> 4, l16 = lane & 15;
  const int trow = wave * 16 + quad * 4;

  __shared__ __align__(16) bf16_t lsXT[32][72];   // X^T slice [dv32][t]
  __shared__ __align__(16) bf16_t lsS[32][136];   // S^T slice [dv32][dk]

  const bf16_t* Wbase = (h < 16 ? Wlo : Whi) + (size_t)(h & 15) * 64 * 8192;
  const bf16_t* Vbase = VtT + (size_t)h * 64 * 8192;
  const bf16_t* Mbase = Mg + (size_t)h * 64 * 4096;
  const bf16_t* Kbase = kt2 + (size_t)h * 64 * 8192;
  const float*  Sbase = smalls + (size_t)h * 64 * 128;

  floatx4 sacc[2][2] = {};
  for (int i = tid; i < 32 * 136; i += 256) (&lsS[0][0])[i] = (bf16_t)0.f;

  bf16x8 nW[4], nQ[4], nK[4], nM[2];
  bf16x4 nV[2];
  float4 nA;
  float nAL;
  chain_prefetch(0, wave, l16, quad, trow, dv0, kh, Wbase, Vbase, Mbase, qg, Kbase,
                 Sbase, nW, nQ, nK, nM, nV, nA, nAL);
  __syncthreads();

  for (int cc = 0; cc < 64; ++cc) {
    const int t0 = cc * 64;
    bf16x8 cW[4], cQ[4], cK[4], cM[2];
    float cV[8];
    float4 cA = nA;
    float cAL = nAL;
#pragma unroll
    for (int ks = 0; ks < 4; ++ks) { cW[ks] = nW[ks]; cQ[ks] = nQ[ks]; cK[ks] = nK[ks]; }
    cM[0] = nM[0]; cM[1] = nM[1];
#pragma unroll
    for (int tn = 0; tn < 2; ++tn)
#pragma unroll
      for (int r = 0; r < 4; ++r) cV[tn * 4 + r] = (float)nV[tn][r];

    if (cc + 1 < 64)
      chain_prefetch(cc + 1, wave, l16, quad, trow, dv0, kh, Wbase, Vbase, Mbase,
                     qg, Kbase, Sbase, nW, nQ, nK, nM, nV, nA, nAL);

    // ---- P0: X = Vt + W'.S  (bS kept for P1's Q.S)
    bf16x8 bS[4][2];
#pragma unroll
    for (int ks = 0; ks < 4; ++ks)
#pragma unroll
      for (int tn = 0; tn < 2; ++tn)
        bS[ks][tn] = *(const bf16x8*)&lsS[tn * 16 + l16][ks * 32 + quad * 8];
    floatx4 xacc[2];
#pragma unroll
    for (int tn = 0; tn < 2; ++tn)
#pragma unroll
      for (int r = 0; r < 4; ++r) xacc[tn][r] = cV[tn * 4 + r];
#pragma unroll
    for (int ks = 0; ks < 4; ++ks)
#pragma unroll
      for (int tn = 0; tn < 2; ++tn)
        xacc[tn] = MFMA16(cW[ks], bS[ks][tn], xacc[tn]);
#pragma unroll
    for (int tn = 0; tn < 2; ++tn) {
      bf16x4 px;
#pragma unroll
      for (int r = 0; r < 4; ++r) px[r] = (bf16_t)xacc[tn][r];
      *(bf16x4*)&lsXT[tn * 16 + l16][trow] = px;
    }
    barrier_lds();  // B1: X ready; lsS reads done

    // ---- P1: o = A*(Q.S) + M.X ; S' = aL*S + KT2.X
    bf16x8 bX[2][2];
#pragma unroll
    for (int ks = 0; ks < 2; ++ks)
#pragma unroll
      for (int tn = 0; tn < 2; ++tn)
        bX[ks][tn] = *(const bf16x8*)&lsXT[tn * 16 + l16][ks * 32 + quad * 8];
    floatx4 qacc[2] = {};
#pragma unroll
    for (int ks = 0; ks < 4; ++ks)
#pragma unroll
      for (int tn = 0; tn < 2; ++tn)
        qacc[tn] = MFMA16(cQ[ks], bS[ks][tn], qacc[tn]);
#pragma unroll
    for (int tn = 0; tn < 2; ++tn)
#pragma unroll
      for (int r = 0; r < 4; ++r) qacc[tn][r] *= ((const float*)&cA)[r];
#pragma unroll
    for (int ks = 0; ks < 2; ++ks)
#pragma unroll
      for (int tn = 0; tn < 2; ++tn)
        qacc[tn] = MFMA16(cM[ks], bX[ks][tn], qacc[tn]);
#pragma unroll
    for (int tn = 0; tn < 2; ++tn)
#pragma unroll
      for (int r = 0; r < 4; ++r)
        o[((size_t)(t0 + trow + r) * 32 + h) * 128 + dv0 + tn * 16 + l16] =
            (bf16_t)qacc[tn][r];
#pragma unroll
    for (int mh = 0; mh < 2; ++mh)
#pragma unroll
      for (int tn = 0; tn < 2; ++tn)
#pragma unroll
        for (int r = 0; r < 4; ++r) sacc[mh][tn][r] *= cAL;
#pragma unroll
    for (int ks = 0; ks < 2; ++ks)
#pragma unroll
      for (int mh = 0; mh < 2; ++mh)
#pragma unroll
        for (int tn = 0; tn < 2; ++tn)
          sacc[mh][tn] = MFMA16(cK[mh * 2 + ks], bX[ks][tn], sacc[mh][tn]);
    // ---- P2: refresh bf16 state (all lsS reads happened before B1)
#pragma unroll
    for (int mh = 0; mh < 2; ++mh)
#pragma unroll
      for (int tn = 0; tn < 2; ++tn) {
        bf16x4 ps;
#pragma unroll
        for (int r = 0; r < 4; ++r) ps[r] = (bf16_t)sacc[mh][tn][r];
        *(bf16x4*)&lsS[tn * 16 + l16][(wave + 4 * mh) * 16 + quad * 4] = ps;
      }
    barrier_lds();  // B2
  }
}

// ---------------------------------------------------------------- RMSNorm * silu(z)
__global__ __launch_bounds__(256) void k_gate(const bf16_t* __restrict__ o,
                                              const bf16_t* __restrict__ z,
                                              const float* __restrict__ nw,
                                              bf16_t* __restrict__ y) {
  const int row = blockIdx.x * 4 + (threadIdx.x >> 6);  // t*32+h
  const int l = threadIdx.x & 63;
  const bf16_t* orow = o + (size_t)row * 128;
  float o0 = (float)orow[l], o1 = (float)orow[l + 64];
  float s = o0 * o0 + o1 * o1;
#pragma unroll
  for (int m = 1; m < 64; m <<= 1) s += __shfl_xor(s, m);
  float r = rsqrtf(s * (1.f / 128.f) + 1e-6f);
  const bf16_t* zrow = z + (size_t)row * 128;
  float z0 = (float)zrow[l], z1 = (float)zrow[l + 64];
  bf16_t* yrow = y + (size_t)row * 128;
  yrow[l]      = (bf16_t)(o0 * r * nw[l] * siluf(z0));
  yrow[l + 64] = (bf16_t)(o1 * r * nw[l + 64] * siluf(z1));
}

// ---------------------------------------------------------------- launch
extern "C" void kernel_launch(void* const* d_in, const int* in_sizes, int n_in,
                              void* d_out, int out_size, void* d_ws, size_t ws_size,
                              hipStream_t stream) {
  const float* hidden = (const float*)d_in[0];
  const float* W_qkv  = (const float*)d_in[1];
  const float* W_z    = (const float*)d_in[2];
  const float* W_b    = (const float*)d_in[3];
  const float* W_a    = (const float*)d_in[4];
  const float* conv_w = (const float*)d_in[5];
  const float* dt_b   = (const float*)d_in[6];
  const float* A_log  = (const float*)d_in[7];
  const float* norm_w = (const float*)d_in[8];
  const float* W_out  = (const float*)d_in[9];
  float* out = (float*)d_out;

  char* w = (char*)d_ws;
  const size_t MB = 1024 * 1024;
  // time-disjoint overlays:
  bf16_t* hs    = (bf16_t*)(w + 0 * MB);     // 16MB -> Wlo (prep out)
  bf16_t* Wlo   = hs;
  bf16_t* wqkv  = (bf16_t*)(w + 16 * MB);    // 32MB -> VtT (prep) -> ybuf (gate)
  bf16_t* Vtb   = wqkv;
  bf16_t* ybuf  = wqkv;
  bf16_t* wz    = (bf16_t*)(w + 48 * MB);    // 16MB -> Whi
  bf16_t* Whi   = wz;
  bf16_t* wout  = (bf16_t*)(w + 64 * MB);    // 16MB (live till end)
  bf16_t* wba   = (bf16_t*)(w + 80 * MB);    // 0.5MB
  bf16_t* mixed = (bf16_t*)(w + 81 * MB);    // 64MB (proj out); after conv:
  bf16_t* kt2b  = (bf16_t*)(w + 81 * MB);    //   KT2 32MB [81,113)
  bf16_t* Mbuf  = (bf16_t*)(w + 113 * MB);   //   M 16MB  [113,129)
  bf16_t* zbuf  = (bf16_t*)(w + 145 * MB);   // 32MB (live till gate)
  float*  cba   = (float*)(w + 177 * MB);    // 2MB -> smalls
  float*  smalls= cba;
  bf16_t* qb    = (bf16_t*)(w + 179 * MB);   // 16MB (live till chain)
  bf16_t* kb    = (bf16_t*)(w + 195 * MB);   // 16MB (prep in)
  bf16_t* vb    = (bf16_t*)(w + 211 * MB);   // 32MB (prep in) -> obuf (chain out)
  bf16_t* obuf  = vb;
  float*  betab = (float*)(w + 243 * MB);    // 0.5MB [h][t]
  float*  gbuf  = (float*)(w + 243 * MB + 512 * 1024);  // 0.5MB [h][t]

  k_cvt_all<<<40960, 256, 0, stream>>>(hidden, W_qkv, W_z, W_out, hs, wqkv, wz, wout);
  k_build_wba<<<256, 256, 0, stream>>>(W_b, W_a, wba);

  gemm_fused<<<dim3(97, 32), 256, 0, stream>>>(hs, wqkv, wz, wba, mixed, zbuf, cba);
  k_betag<<<512, 256, 0, stream>>>(cba, A_log, dt_b, betab, gbuf);

  k_conv<<<dim3(64, 512), 64, 0, stream>>>(mixed, conv_w, qb, kb, vb);

  k_prep<<<2048, 256, 0, stream>>>(qb, kb, vb, betab, gbuf,
                                   Vtb, Wlo, Whi, Mbuf, kt2b, smalls);
  k_chain<<<128, 256, 0, stream>>>(qb, Vtb, Wlo, Whi, Mbuf, kt2b, smalls, obuf);

  k_gate<<<32768, 256, 0, stream>>>(obuf, zbuf, norm_w, ybuf);
  gemm_out<<<dim3(16, 32), 256, 0, stream>>>(ybuf, wout, out, 2048, 4096);
}